// Round 7
// baseline (105.826 us; speedup 1.0000x reference)
//
#include <hip/hip_runtime.h>
#include <hip/hip_bf16.h>
#include <math.h>

#define KMIX 16
#define DIM  16
#define TPW  8          // 16-sample tiles per wave
typedef _Float16 half8 __attribute__((ext_vector_type(8)));
typedef float    f32x4 __attribute__((ext_vector_type(4)));

// ---------------------------------------------------------------------------
// Single fused kernel (R7). Phase 1: each block redundantly computes mixture
// constants with the R6-verified cooperative shfl Cholesky — 16 lane-groups
// (4 waves x 4 quads) = 16 mixtures, lane r owns row r; all per-lane arrays
// are 16 floats with compile-time indices (pure VGPR, no scratch — R5's
// fusion failed because its body was the scratch-array version), cross-lane
// via __shfl. Groups write PRE-PACKED half8 A-operand fragments to LDS.
// Phase 2: unchanged MFMA main loop; afrag = conflict-free ds_read_b128.
// One graph node; d_ws unused.
// ---------------------------------------------------------------------------
__global__ __launch_bounds__(256) void gmm_fused(
    const float* __restrict__ samples,
    const float* __restrict__ Phi, const float* __restrict__ mu,
    const float* __restrict__ Sigma,
    float* __restrict__ out, int N, int ntiles)
{
    __shared__ half8 sW[KMIX][64];     // packed A fragments, 16 KB
    __shared__ float sCk[KMIX];

    const int tid  = threadIdx.x;
    const int lane = tid & 63;
    const int r    = lane & 15;        // row within group
    const int base = lane & 48;        // 16-lane group base within wave
    const int wv   = tid >> 6;         // wave index in block (0..3)
    const int quad = lane >> 4;
    const int k    = wv * 4 + quad;    // this group's mixture (0..15)

    // ---- Phase 1: cooperative Cholesky + triangular inverse (per group) ----
    float l[DIM];
    {
        const float4* p = (const float4*)(Sigma + k * 256 + r * 16);
        const float4 a = p[0], b = p[1], c = p[2], d = p[3];
        l[0]=a.x;  l[1]=a.y;  l[2]=a.z;  l[3]=a.w;
        l[4]=b.x;  l[5]=b.y;  l[6]=b.z;  l[7]=b.w;
        l[8]=c.x;  l[9]=c.y;  l[10]=c.z; l[11]=c.w;
        l[12]=d.x; l[13]=d.y; l[14]=d.z; l[15]=d.w;
    }

    // Cholesky: after step j, l[j] on lanes r>=j is final L[r][j].
    float rd_own = 0.0f;               // rcp(L[r][r]), set at step r
    #pragma unroll
    for (int j = 0; j < DIM; ++j) {
        const float dj  = __builtin_amdgcn_sqrtf(l[j]);   // meaningful on lane j
        const float rdj = __builtin_amdgcn_rcpf(dj);
        if (r == j) { l[j] = dj; rd_own = rdj; }
        const float rdb = __shfl(rdj, base + j, 64);
        if (r > j) l[j] *= rdb;        // final L[r][j]
        #pragma unroll
        for (int c = j + 1; c < DIM; ++c) {
            const float Lcj = __shfl(l[j], base + c, 64);  // L[c][j]
            if (r >= c) l[c] = fmaf(-l[j], Lcj, l[c]);     // rank-1 update
        }
    }

    // Triangular inverse V = L^{-1}, lane r builds row r.
    float v[DIM], acc[DIM];
    #pragma unroll
    for (int c = 0; c < DIM; ++c) { v[c] = 0.0f; acc[c] = 0.0f; }
    #pragma unroll
    for (int m = 0; m < DIM; ++m) {
        if (r == m) {
            #pragma unroll
            for (int c = 0; c < DIM; ++c)
                if (c < m) v[c] = -rd_own * acc[c];
            v[m] = rd_own;
        }
        #pragma unroll
        for (int c = 0; c <= m; ++c) {
            const float Vmc = __shfl(v[c], base + m, 64);
            if (r > m) acc[c] = fmaf(l[m], Vmc, acc[c]);
        }
    }

    // coeff = Phi / (sqrt(2*pi) * prod diag L)
    float prod = rd_own;
    prod *= __shfl_xor(prod, 1, 64);
    prod *= __shfl_xor(prod, 2, 64);
    prod *= __shfl_xor(prod, 4, 64);
    prod *= __shfl_xor(prod, 8, 64);
    if (r == 0) sCk[k] = Phi[k] * 0.3989422804014327f * prod;

    // b_r = sum_c V[r][c] mu[c]  (v[c]=0 for c>r)
    float b = 0.0f;
    {
        const float4* pm = (const float4*)(mu + k * DIM);
        const float4 m0 = pm[0], m1 = pm[1], m2 = pm[2], m3 = pm[3];
        const float mv[DIM] = {m0.x,m0.y,m0.z,m0.w, m1.x,m1.y,m1.z,m1.w,
                               m2.x,m2.y,m2.z,m2.w, m3.x,m3.y,m3.z,m3.w};
        #pragma unroll
        for (int c = 0; c < DIM; ++c) b = fmaf(v[c], mv[c], b);
    }

    // Pack A fragments (verified 16x16x32 A layout: A[m=lane&15][k=quad*8+j],
    // W~ = [L^{-1} | -b | 0]); output lanes {q*16+r} all source row r.
    {
        half8 h0, h1, h2, h3;
        #pragma unroll
        for (int j = 0; j < 8; ++j) {
            h0[j] = (_Float16)v[j];
            h1[j] = (_Float16)v[8 + j];
            h2[j] = (_Float16)0.0f;
            h3[j] = (_Float16)0.0f;
        }
        h2[0] = (_Float16)(-b);
        sW[k][r]      = h0;
        sW[k][16 + r] = h1;
        sW[k][32 + r] = h2;
        sW[k][48 + r] = h3;
    }
    __syncthreads();

    // ---- Phase 2: MFMA main loop (verified since R3) ----
    const int n = lane & 15;           // sample column within tile
    const int wave = blockIdx.x * 4 + wv;

    half8 afrag[KMIX];
    #pragma unroll
    for (int mix = 0; mix < KMIX; ++mix) afrag[mix] = sW[mix][lane];
    float ck[KMIX];
    #pragma unroll
    for (int mix = 0; mix < KMIX; ++mix) ck[mix] = sCk[mix];

    const f32x4 zero = {0.0f, 0.0f, 0.0f, 0.0f};

    for (int t = 0; t < TPW; ++t) {
        const int tile = wave * TPW + t;
        if (tile >= ntiles) break;
        const int s0 = tile * 16;

        half8 bfrag;
        #pragma unroll
        for (int j = 0; j < 8; ++j) bfrag[j] = (_Float16)0.0f;
        if (quad < 2) {
            int sidx = s0 + n; if (sidx >= N) sidx = N - 1;
            const float4* p = (const float4*)(samples + (size_t)sidx * DIM + quad * 8);
            const float4 u = p[0], w = p[1];
            bfrag[0] = (_Float16)u.x; bfrag[1] = (_Float16)u.y;
            bfrag[2] = (_Float16)u.z; bfrag[3] = (_Float16)u.w;
            bfrag[4] = (_Float16)w.x; bfrag[5] = (_Float16)w.y;
            bfrag[6] = (_Float16)w.z; bfrag[7] = (_Float16)w.w;
        } else if (quad == 2) {
            bfrag[0] = (_Float16)1.0f;   // augmented k=16 -> folds -b
        }

        float sum = 0.0f;
        #pragma unroll
        for (int mix = 0; mix < KMIX; ++mix) {
            const f32x4 d = __builtin_amdgcn_mfma_f32_16x16x32_f16(
                afrag[mix], bfrag, zero, 0, 0, 0);
            float q = d[0] * d[0];
            q = fmaf(d[1], d[1], q);
            q = fmaf(d[2], d[2], q);
            q = fmaf(d[3], d[3], q);
            q += __shfl_xor(q, 16, 64);
            q += __shfl_xor(q, 32, 64);
            sum = fmaf(ck[mix], __expf(-0.5f * q), sum);
        }

        const int sidx = s0 + n;
        if (quad == 0 && sidx < N) out[sidx] = -__logf(sum);
    }
}

extern "C" void kernel_launch(void* const* d_in, const int* in_sizes, int n_in,
                              void* d_out, int out_size, void* d_ws, size_t ws_size,
                              hipStream_t stream)
{
    const float* samples = (const float*)d_in[0];
    const float* Phi     = (const float*)d_in[1];
    const float* mu      = (const float*)d_in[2];
    const float* Sigma   = (const float*)d_in[3];
    float* out = (float*)d_out;
    const int N = in_sizes[0] / DIM;

    const int ntiles = (N + 15) / 16;               // 32768
    const int waves  = (ntiles + TPW - 1) / TPW;    // 4096
    const int blocks = (waves + 3) / 4;             // 1024

    gmm_fused<<<blocks, 256, 0, stream>>>(samples, Phi, mu, Sigma, out, N, ntiles);
}

// Round 8
// 99.798 us; speedup vs baseline: 1.0604x; 1.0604x over previous
//
#include <hip/hip_runtime.h>
#include <hip/hip_bf16.h>
#include <math.h>

#define KMIX 16
#define DIM  16
#define TPW  8          // 16-sample tiles per wave in gmm_main

typedef _Float16 half8 __attribute__((ext_vector_type(8)));
typedef float    f32x4 __attribute__((ext_vector_type(4)));

// ---------------------------------------------------------------------------
// R8 = R6 verbatim (best measured: 99.9 us). R7's fusion experiment proved
// the residual ~30 us is per-replay overhead insensitive to kernel/node
// structure, so the two-kernel R6 config is the controllable optimum.
//
// Precompute, cooperative: 4 blocks x 64 threads; each 16-lane group owns one
// mixture, lane r owns ROW r. All per-lane arrays are 16 floats with
// compile-time indices -> pure VGPR (no scratch); cross-lane via __shfl.
// ---------------------------------------------------------------------------
__global__ __launch_bounds__(64) void gmm_precompute(
    const float* __restrict__ Phi, const float* __restrict__ mu,
    const float* __restrict__ Sigma,
    _Float16* __restrict__ wsA, float* __restrict__ wsC)
{
    const int lane = threadIdx.x;
    const int r    = lane & 15;
    const int base = lane & 48;                 // 16-lane group base in wave
    const int k    = blockIdx.x * 4 + (lane >> 4);

    // Row r of Sigma_k.
    float l[DIM];
    {
        const float4* p = (const float4*)(Sigma + k * 256 + r * 16);
        const float4 a = p[0], b = p[1], c = p[2], d = p[3];
        l[0]=a.x;  l[1]=a.y;  l[2]=a.z;  l[3]=a.w;
        l[4]=b.x;  l[5]=b.y;  l[6]=b.z;  l[7]=b.w;
        l[8]=c.x;  l[9]=c.y;  l[10]=c.z; l[11]=c.w;
        l[12]=d.x; l[13]=d.y; l[14]=d.z; l[15]=d.w;
    }

    // Cholesky: after step j, l[j] on lanes r>=j is final L[r][j].
    float rd_own = 0.0f;                        // rcp(L[r][r]), set at step r
    #pragma unroll
    for (int j = 0; j < DIM; ++j) {
        const float dj  = __builtin_amdgcn_sqrtf(l[j]);   // meaningful on lane j
        const float rdj = __builtin_amdgcn_rcpf(dj);
        if (r == j) { l[j] = dj; rd_own = rdj; }
        const float rdb = __shfl(rdj, base + j, 64);
        if (r > j) l[j] *= rdb;                 // final L[r][j]
        #pragma unroll
        for (int c = j + 1; c < DIM; ++c) {
            const float Lcj = __shfl(l[j], base + c, 64);  // L[c][j]
            if (r >= c) l[c] = fmaf(-l[j], Lcj, l[c]);     // rank-1 update
        }
    }

    // Triangular inverse V = L^{-1}, lane r builds row r.
    // acc[c] accumulates sum_{m=c}^{r-1} L[r][m] * V[m][c].
    float v[DIM], acc[DIM];
    #pragma unroll
    for (int c = 0; c < DIM; ++c) { v[c] = 0.0f; acc[c] = 0.0f; }
    #pragma unroll
    for (int m = 0; m < DIM; ++m) {
        if (r == m) {                           // finalize row m
            #pragma unroll
            for (int c = 0; c < DIM; ++c)
                if (c < m) v[c] = -rd_own * acc[c];
            v[m] = rd_own;
        }
        #pragma unroll
        for (int c = 0; c <= m; ++c) {          // broadcast row m, accumulate
            const float Vmc = __shfl(v[c], base + m, 64);
            if (r > m) acc[c] = fmaf(l[m], Vmc, acc[c]);
        }
    }

    // coeff = Phi / (sqrt(2*pi) * prod diag L)  (prod rd across the group)
    float prod = rd_own;
    prod *= __shfl_xor(prod, 1, 64);
    prod *= __shfl_xor(prod, 2, 64);
    prod *= __shfl_xor(prod, 4, 64);
    prod *= __shfl_xor(prod, 8, 64);
    if (r == 0) wsC[k] = Phi[k] * 0.3989422804014327f * prod;

    // b_r = sum_c V[r][c] mu[c]   (v[c]=0 for c>r, so no predicate needed)
    float b = 0.0f;
    {
        const float4* pm = (const float4*)(mu + k * DIM);
        const float4 m0 = pm[0], m1 = pm[1], m2 = pm[2], m3 = pm[3];
        const float mv[DIM] = {m0.x,m0.y,m0.z,m0.w, m1.x,m1.y,m1.z,m1.w,
                               m2.x,m2.y,m2.z,m2.w, m3.x,m3.y,m3.z,m3.w};
        #pragma unroll
        for (int c = 0; c < DIM; ++c) b = fmaf(v[c], mv[c], b);
    }

    // Pack A-operand fragments (verified 16x16x32 A layout:
    // A[m=lane&15][k=quad*8+j], W~ = [L^{-1} | -b | 0]). Output lanes
    // {q*16 + r} all need row r -> this lane writes all four.
    half8 h0, h1, h2, h3;
    #pragma unroll
    for (int j = 0; j < 8; ++j) {
        h0[j] = (_Float16)v[j];
        h1[j] = (_Float16)v[8 + j];
        h2[j] = (_Float16)0.0f;
        h3[j] = (_Float16)0.0f;
    }
    h2[0] = (_Float16)(-b);
    half8* W = (half8*)wsA + k * 64;
    W[r]      = h0;
    W[16 + r] = h1;
    W[32 + r] = h2;
    W[48 + r] = h3;
}

// ---------------------------------------------------------------------------
// Main (verified since R3): per wave, per 16-sample tile: build
// B frag = [x;1;0-pad], one MFMA per mixture, q = 4 square-FMAs +
// shfl_xor(16) + shfl_xor(32), sum_k c_k exp(-q/2).
// ---------------------------------------------------------------------------
__global__ __launch_bounds__(256) void gmm_main(
    const float* __restrict__ samples,
    const _Float16* __restrict__ wsA, const float* __restrict__ wsC,
    float* __restrict__ out, int N, int ntiles)
{
    const int lane = threadIdx.x & 63;
    const int wave = blockIdx.x * (blockDim.x >> 6) + (threadIdx.x >> 6);
    const int n = lane & 15;          // sample column within tile
    const int quad = lane >> 4;

    half8 afrag[KMIX];
    #pragma unroll
    for (int mix = 0; mix < KMIX; ++mix)
        afrag[mix] = ((const half8*)wsA)[mix * 64 + lane];
    float ck[KMIX];
    #pragma unroll
    for (int mix = 0; mix < KMIX; ++mix) ck[mix] = wsC[mix];

    const f32x4 zero = {0.0f, 0.0f, 0.0f, 0.0f};

    for (int t = 0; t < TPW; ++t) {
        const int tile = wave * TPW + t;
        if (tile >= ntiles) break;
        const int s0 = tile * 16;

        half8 bfrag;
        #pragma unroll
        for (int j = 0; j < 8; ++j) bfrag[j] = (_Float16)0.0f;
        if (quad < 2) {
            int sidx = s0 + n; if (sidx >= N) sidx = N - 1;
            const float4* p = (const float4*)(samples + (size_t)sidx * DIM + quad * 8);
            const float4 u = p[0], v = p[1];
            bfrag[0] = (_Float16)u.x; bfrag[1] = (_Float16)u.y;
            bfrag[2] = (_Float16)u.z; bfrag[3] = (_Float16)u.w;
            bfrag[4] = (_Float16)v.x; bfrag[5] = (_Float16)v.y;
            bfrag[6] = (_Float16)v.z; bfrag[7] = (_Float16)v.w;
        } else if (quad == 2) {
            bfrag[0] = (_Float16)1.0f;   // augmented k=16 -> folds -b
        }

        float sum = 0.0f;
        #pragma unroll
        for (int mix = 0; mix < KMIX; ++mix) {
            const f32x4 d = __builtin_amdgcn_mfma_f32_16x16x32_f16(
                afrag[mix], bfrag, zero, 0, 0, 0);
            float q = d[0] * d[0];
            q = fmaf(d[1], d[1], q);
            q = fmaf(d[2], d[2], q);
            q = fmaf(d[3], d[3], q);
            q += __shfl_xor(q, 16, 64);
            q += __shfl_xor(q, 32, 64);
            sum = fmaf(ck[mix], __expf(-0.5f * q), sum);
        }

        const int sidx = s0 + n;
        if (quad == 0 && sidx < N) out[sidx] = -__logf(sum);
    }
}

extern "C" void kernel_launch(void* const* d_in, const int* in_sizes, int n_in,
                              void* d_out, int out_size, void* d_ws, size_t ws_size,
                              hipStream_t stream)
{
    const float* samples = (const float*)d_in[0];
    const float* Phi     = (const float*)d_in[1];
    const float* mu      = (const float*)d_in[2];
    const float* Sigma   = (const float*)d_in[3];
    float* out = (float*)d_out;
    const int N = in_sizes[0] / DIM;

    _Float16* wsA = (_Float16*)d_ws;                       // 16*64*8 halves = 16 KB
    float* wsC = (float*)((char*)d_ws + KMIX * 64 * 8 * sizeof(_Float16));

    gmm_precompute<<<4, 64, 0, stream>>>(Phi, mu, Sigma, wsA, wsC);

    const int ntiles = (N + 15) / 16;
    const int waves  = (ntiles + TPW - 1) / TPW;
    const int blocks = (waves + 3) / 4;
    gmm_main<<<blocks, 256, 0, stream>>>(samples, wsA, wsC, out, N, ntiles);
}